// Round 1
// baseline (102638.599 us; speedup 1.0000x reference)
//
#include <hip/hip_runtime.h>

typedef _Float16 f16;
typedef f16  f16x8 __attribute__((ext_vector_type(8)));
typedef float f32x4 __attribute__((ext_vector_type(4)));
typedef unsigned int u32;

#define NBLK   256
#define TPB    512
#define TSTEPS 512
#define NL     5
#define HDIM   1024
#define NROUND (TSTEPS*NL)
#define WSLOT  6
// LDS weights: [slot(6)][kk(32)][p(12)][g*8+i(32)] halfs
#define LW_HALFS (WSLOT*32*12*32)          // 73728 halfs = 147456 B
#define LDS_RED_OFF 147456
#define SMEM_BYTES  (147456 + 4096)        // 151552 B

__device__ __forceinline__ float fsigmoid(float v){ return 1.0f/(1.0f + __expf(-v)); }
__device__ __forceinline__ float ftanh(float v){ return 1.0f - 2.0f/(__expf(2.0f*v) + 1.0f); }

// x [B][T][K] f32 -> xT [T][B][K] f16
__global__ void cvt_x_kernel(const float* __restrict__ x, f16* __restrict__ xT){
    const size_t idx = (size_t)blockIdx.x*blockDim.x + threadIdx.x;  // 4,194,304 threads, 8 elems each
    const size_t e = idx*8;
    const int k  = (int)(e & 1023);
    const int tt = (int)((e >> 10) & 511);
    const int b  = (int)(e >> 19);
    const float4 v0 = *(const float4*)(x + e);
    const float4 v1 = *(const float4*)(x + e + 4);
    f16x8 o;
    o[0]=(f16)v0.x; o[1]=(f16)v0.y; o[2]=(f16)v0.z; o[3]=(f16)v0.w;
    o[4]=(f16)v1.x; o[5]=(f16)v1.y; o[6]=(f16)v1.z; o[7]=(f16)v1.w;
    *(f16x8*)(xT + ((size_t)tt*64 + b)*HDIM + k) = o;
}

template<bool USE_XT>
__global__ __launch_bounds__(TPB, 2)
void rhn_persistent(const float* __restrict__ x,   // f32 [64][512][1024], used if !USE_XT
                    const f16*  __restrict__ xT,   // f16 [512][64][1024], used if USE_XT
                    const float* __restrict__ s0,
                    const float* __restrict__ w_h, const float* __restrict__ w_t, const float* __restrict__ w_c,
                    const float* __restrict__ r_hw, const float* __restrict__ r_tw, const float* __restrict__ r_cw,
                    const float* __restrict__ r_hb, const float* __restrict__ r_tb, const float* __restrict__ r_cb,
                    f16* __restrict__ sb0, f16* __restrict__ sb1,
                    u32* __restrict__ flags,
                    float* __restrict__ out)
{
    extern __shared__ char smem[];
    f16*   lw  = (f16*)smem;
    f32x4* red = (f32x4*)(smem + LDS_RED_OFF);   // [4 waves][64 lanes]

    const int tid = threadIdx.x;
    const int ln  = tid & 63;
    const int wid = tid >> 6;
    const int mt  = wid & 3;   // M-tile (batches mt*16..+16)
    const int kh  = wid >> 2;  // K-half (0: k<512, 1: k>=512)
    const int c   = blockIdx.x;
    const int g   = ln >> 4;   // k-group within 32-k tile
    const int p   = ln & 15;   // packed col: 0-3 h, 4-7 t, 8-11 c, 12-15 pad
    const int pe  = (p < 12) ? p : 11;

    // ---------------- prologue: LDS weight fill ----------------
    for (int s = 0; s < WSLOT; ++s) {
        for (int mu = 0; mu < 3; ++mu) {
            const float* W;
            if (s < NL) W = (mu==0 ? r_hw : (mu==1 ? r_tw : r_cw)) + (size_t)s*HDIM*HDIM;
            else        W = (mu==0 ? w_h  : (mu==1 ? w_t  : w_c));
            for (int k = tid; k < HDIM; k += TPB) {
                const float4 v = *(const float4*)(W + (size_t)k*HDIM + 4*c);  // cols 4c..4c+3
                const int kk = k >> 5, gg = (k >> 3) & 3, ii = k & 7;
                f16* dst = lw + ((s*32 + kk)*12 + mu*4)*32 + gg*8 + ii;
                dst[0]  = (f16)v.x;
                dst[32] = (f16)v.y;
                dst[64] = (f16)v.z;
                dst[96] = (f16)v.w;
            }
        }
    }

    // per-lane ownership for update waves (kh==0): lane -> (batch row R, col jj)
    const int R    = ln >> 2;
    const int jj   = ln & 3;
    const int jcol = 4*c + jj;
    const int bat  = mt*16 + R;
    float s_cur = 0.f;
    float bh[NL], bt[NL], bc[NL];
    if (kh == 0) {
        s_cur = s0[(size_t)bat*HDIM + jcol];
        #pragma unroll
        for (int l = 0; l < NL; ++l) {
            bh[l] = r_hb[l*HDIM + jcol];
            bt[l] = r_tb[l*HDIM + jcol];
            bc[l] = r_cb[l*HDIM + jcol];
        }
        sb0[(size_t)bat*HDIM + jcol] = (f16)s_cur;
        __builtin_amdgcn_fence(__ATOMIC_RELEASE, "agent");
    }
    __syncthreads();
    if (tid == 0)
        __hip_atomic_store(&flags[c], 1u, __ATOMIC_RELAXED, __HIP_MEMORY_SCOPE_AGENT);

    const f16* sbufs[2] = { sb0, sb1 };
    const int arow = mt*16 + p;   // A-fragment batch row (row = lane%16)
    int t = 0, l = 0;
    unsigned guard = 0;

    for (int r = 0; r < NROUND; ++r) {
        // ---- wait: only the 128 producer blocks of my K-half ----
        const u32 tgt = (u32)(r + 1);
        if (guard < (1u<<22)) {
            for (;;) {
                u32 f0 = __hip_atomic_load(&flags[kh*128 + ln],      __ATOMIC_RELAXED, __HIP_MEMORY_SCOPE_AGENT);
                u32 f1 = __hip_atomic_load(&flags[kh*128 + 64 + ln], __ATOMIC_RELAXED, __HIP_MEMORY_SCOPE_AGENT);
                if (__all(f0 >= tgt && f1 >= tgt)) break;
                if (++guard >= (1u<<22)) break;   // safety: never hang
                __builtin_amdgcn_s_sleep(2);
            }
        }
        __builtin_amdgcn_fence(__ATOMIC_ACQUIRE, "agent");

        const f16* sb = sbufs[r & 1];
        f32x4 acc = {0.f,0.f,0.f,0.f};
        {
            const f16* ap = sb + (size_t)arow*HDIM + kh*512 + g*8;
            const f16* bp = lw + ((l*32 + kh*16)*12 + pe)*32 + g*8;
            #pragma unroll
            for (int kk = 0; kk < 16; ++kk) {
                f16x8 a = *(const f16x8*)(ap + kk*32);
                f16x8 b = *(const f16x8*)(bp + kk*384);
                acc = __builtin_amdgcn_mfma_f32_16x16x32_f16(a, b, acc, 0, 0, 0);
            }
        }
        if (l == 0) {  // fold input projections into layer 0 (slot 5)
            const f16* bp = lw + ((5*32 + kh*16)*12 + pe)*32 + g*8;
            if (USE_XT) {
                const f16* ap = xT + ((size_t)t*64 + arow)*HDIM + kh*512 + g*8;
                #pragma unroll
                for (int kk = 0; kk < 16; ++kk) {
                    f16x8 a = *(const f16x8*)(ap + kk*32);
                    f16x8 b = *(const f16x8*)(bp + kk*384);
                    acc = __builtin_amdgcn_mfma_f32_16x16x32_f16(a, b, acc, 0, 0, 0);
                }
            } else {
                const float* ap = x + ((size_t)arow*TSTEPS + t)*HDIM + kh*512 + g*8;
                #pragma unroll
                for (int kk = 0; kk < 16; ++kk) {
                    float4 v0 = *(const float4*)(ap + kk*32);
                    float4 v1 = *(const float4*)(ap + kk*32 + 4);
                    f16x8 a;
                    a[0]=(f16)v0.x; a[1]=(f16)v0.y; a[2]=(f16)v0.z; a[3]=(f16)v0.w;
                    a[4]=(f16)v1.x; a[5]=(f16)v1.y; a[6]=(f16)v1.z; a[7]=(f16)v1.w;
                    f16x8 b = *(const f16x8*)(bp + kk*384);
                    acc = __builtin_amdgcn_mfma_f32_16x16x32_f16(a, b, acc, 0, 0, 0);
                }
            }
        }
        if (kh == 1) red[mt*64 + ln] = acc;
        __syncthreads();
        if (kh == 0) {
            acc += red[mt*64 + ln];
            // redistribute: lane u=(R,jj) gathers H/T/C from lanes (R>>2)*16 + jj + {0,4,8}, reg R&3
            const int sl = (R >> 2)*16 + jj;
            const int ri = R & 3;
            float hv, tv, cv;
            { float v0=__shfl(acc[0],sl),   v1=__shfl(acc[1],sl),   v2=__shfl(acc[2],sl),   v3=__shfl(acc[3],sl);
              hv = ri==0?v0: ri==1?v1: ri==2?v2: v3; }
            { float v0=__shfl(acc[0],sl+4), v1=__shfl(acc[1],sl+4), v2=__shfl(acc[2],sl+4), v3=__shfl(acc[3],sl+4);
              tv = ri==0?v0: ri==1?v1: ri==2?v2: v3; }
            { float v0=__shfl(acc[0],sl+8), v1=__shfl(acc[1],sl+8), v2=__shfl(acc[2],sl+8), v3=__shfl(acc[3],sl+8);
              cv = ri==0?v0: ri==1?v1: ri==2?v2: v3; }
            hv += bh[l]; tv += bt[l]; cv += bc[l];
            const float hh = ftanh(hv);
            const float tg = fsigmoid(tv);
            const float cg = fsigmoid(cv);
            const float s_new = hh*tg + s_cur*cg;
            s_cur = s_new;
            f16* sbn = (f16*)sbufs[(r + 1) & 1];
            sbn[(size_t)bat*HDIM + jcol] = (f16)s_new;
            if (l == NL-1) out[((size_t)bat*TSTEPS + t)*HDIM + jcol] = s_new;
            __builtin_amdgcn_fence(__ATOMIC_RELEASE, "agent");
        }
        __syncthreads();
        if (tid == 0)
            __hip_atomic_store(&flags[c], (u32)(r + 2), __ATOMIC_RELAXED, __HIP_MEMORY_SCOPE_AGENT);

        if (++l == NL) { l = 0; ++t; }
    }
    // s_final tail
    if (kh == 0)
        out[(size_t)64*TSTEPS*HDIM + (size_t)bat*HDIM + jcol] = s_cur;
}

extern "C" void kernel_launch(void* const* d_in, const int* in_sizes, int n_in,
                              void* d_out, int out_size, void* d_ws, size_t ws_size,
                              hipStream_t stream)
{
    const float* x    = (const float*)d_in[0];
    const float* s0   = (const float*)d_in[1];
    const float* w_h  = (const float*)d_in[2];
    const float* w_t  = (const float*)d_in[3];
    const float* w_c  = (const float*)d_in[4];
    const float* r_hw = (const float*)d_in[5];
    const float* r_tw = (const float*)d_in[6];
    const float* r_cw = (const float*)d_in[7];
    const float* r_hb = (const float*)d_in[8];
    const float* r_tb = (const float*)d_in[9];
    const float* r_cb = (const float*)d_in[10];
    float* out = (float*)d_out;

    char* ws   = (char*)d_ws;
    u32*  flags = (u32*)ws;                                 // 1 KB
    f16*  sb0  = (f16*)(ws + 4096);                         // 128 KB
    f16*  sb1  = (f16*)(ws + 4096 + 131072);                // 128 KB
    f16*  xT   = (f16*)(ws + 4096 + 262144);                // 64 MB
    const size_t need_xt = 4096 + 262144 + (size_t)TSTEPS*64*HDIM*2;
    const bool use_xt = (ws_size >= need_xt);

    hipMemsetAsync(flags, 0, 1024, stream);
    if (use_xt)
        cvt_x_kernel<<<dim3(16384), dim3(256), 0, stream>>>(x, xT);

    hipFuncSetAttribute((const void*)rhn_persistent<true>,
                        hipFuncAttributeMaxDynamicSharedMemorySize, SMEM_BYTES);
    hipFuncSetAttribute((const void*)rhn_persistent<false>,
                        hipFuncAttributeMaxDynamicSharedMemorySize, SMEM_BYTES);

    if (use_xt)
        rhn_persistent<true><<<dim3(NBLK), dim3(TPB), SMEM_BYTES, stream>>>(
            x, xT, s0, w_h, w_t, w_c, r_hw, r_tw, r_cw, r_hb, r_tb, r_cb,
            sb0, sb1, flags, out);
    else
        rhn_persistent<false><<<dim3(NBLK), dim3(TPB), SMEM_BYTES, stream>>>(
            x, xT, s0, w_h, w_t, w_c, r_hw, r_tw, r_cw, r_hb, r_tb, r_cb,
            sb0, sb1, flags, out);
}

// Round 2
// 32597.491 us; speedup vs baseline: 3.1487x; 3.1487x over previous
//
#include <hip/hip_runtime.h>

typedef _Float16 f16;
typedef f16  f16x8 __attribute__((ext_vector_type(8)));
typedef float f32x4 __attribute__((ext_vector_type(4)));
typedef unsigned int u32;
typedef unsigned long long u64;
typedef u64 u64x2 __attribute__((ext_vector_type(2)));

#define NBLK   256
#define TPB    512
#define TSTEPS 512
#define NL     5
#define HDIM   1024
#define NROUND (TSTEPS*NL)
#define WSLOT  6
// LDS weights: [slot(6)][kk(32)][p(12)][g*8+i(32)] halfs
#define LW_HALFS (WSLOT*32*12*32)          // 73728 halfs = 147456 B
#define LDS_RED_OFF 147456
#define SMEM_BYTES  (147456 + 4096)        // 151552 B

__device__ __forceinline__ float fsigmoid(float v){ return 1.0f/(1.0f + __expf(-v)); }
__device__ __forceinline__ float ftanh(float v){ return 1.0f - 2.0f/(__expf(2.0f*v) + 1.0f); }

// x [B][T][K] f32 -> xT [T][B][K] f16
__global__ void cvt_x_kernel(const float* __restrict__ x, f16* __restrict__ xT){
    const size_t idx = (size_t)blockIdx.x*blockDim.x + threadIdx.x;
    const size_t e = idx*8;
    const int k  = (int)(e & 1023);
    const int tt = (int)((e >> 10) & 511);
    const int b  = (int)(e >> 19);
    const float4 v0 = *(const float4*)(x + e);
    const float4 v1 = *(const float4*)(x + e + 4);
    f16x8 o;
    o[0]=(f16)v0.x; o[1]=(f16)v0.y; o[2]=(f16)v0.z; o[3]=(f16)v0.w;
    o[4]=(f16)v1.x; o[5]=(f16)v1.y; o[6]=(f16)v1.z; o[7]=(f16)v1.w;
    *(f16x8*)(xT + ((size_t)tt*64 + b)*HDIM + k) = o;
}

template<bool USE_XT>
__global__ __launch_bounds__(TPB, 2)
void rhn_persistent(const float* __restrict__ x,   // f32 [64][512][1024], used if !USE_XT
                    const f16*  __restrict__ xT,   // f16 [512][64][1024], used if USE_XT
                    const float* __restrict__ s0,
                    const float* __restrict__ w_h, const float* __restrict__ w_t, const float* __restrict__ w_c,
                    const float* __restrict__ r_hw, const float* __restrict__ r_tw, const float* __restrict__ r_cw,
                    const float* __restrict__ r_hb, const float* __restrict__ r_tb, const float* __restrict__ r_cb,
                    f16* __restrict__ sb0, f16* __restrict__ sb1,
                    u32* __restrict__ flags,
                    float* __restrict__ out)
{
    extern __shared__ char smem[];
    f16*   lw  = (f16*)smem;
    f32x4* red = (f32x4*)(smem + LDS_RED_OFF);   // [4 waves][64 lanes]

    const int tid = threadIdx.x;
    const int ln  = tid & 63;
    const int wid = tid >> 6;
    const int mt  = wid & 3;   // M-tile (batches mt*16..+16)
    const int kh  = wid >> 2;  // K-half (0: k<512, 1: k>=512)
    const int c   = blockIdx.x;
    const int g   = ln >> 4;   // k-group within 32-k tile
    const int p   = ln & 15;   // packed col: 0-3 h, 4-7 t, 8-11 c, 12-15 pad
    const int pe  = (p < 12) ? p : 11;

    // ---------------- prologue: LDS weight fill ----------------
    for (int s = 0; s < WSLOT; ++s) {
        for (int mu = 0; mu < 3; ++mu) {
            const float* W;
            if (s < NL) W = (mu==0 ? r_hw : (mu==1 ? r_tw : r_cw)) + (size_t)s*HDIM*HDIM;
            else        W = (mu==0 ? w_h  : (mu==1 ? w_t  : w_c));
            for (int k = tid; k < HDIM; k += TPB) {
                const float4 v = *(const float4*)(W + (size_t)k*HDIM + 4*c);  // cols 4c..4c+3
                const int kk = k >> 5, gg = (k >> 3) & 3, ii = k & 7;
                f16* dst = lw + ((s*32 + kk)*12 + mu*4)*32 + gg*8 + ii;
                dst[0]  = (f16)v.x;
                dst[32] = (f16)v.y;
                dst[64] = (f16)v.z;
                dst[96] = (f16)v.w;
            }
        }
    }

    // per-lane ownership for update waves (kh==0): lane -> (batch row R, col jj)
    const int R    = ln >> 2;
    const int jj   = ln & 3;
    const int jcol = 4*c + jj;
    const int bat  = mt*16 + R;
    float s_cur = 0.f;
    float bh[NL], bt[NL], bc[NL];
    if (kh == 0) {
        s_cur = s0[(size_t)bat*HDIM + jcol];
        #pragma unroll
        for (int l = 0; l < NL; ++l) {
            bh[l] = r_hb[l*HDIM + jcol];
            bt[l] = r_tb[l*HDIM + jcol];
            bc[l] = r_cb[l*HDIM + jcol];
        }
        // packed u32 agent-scope store (LLC-direct, bypasses non-coherent L2)
        union { f16 h; unsigned short u; } cv; cv.h = (f16)s_cur;
        u32 mybits = cv.u;
        u32 otherbits = (u32)(unsigned short)__shfl_xor((int)mybits, 1);
        if ((jj & 1) == 0) {
            u32 packed = mybits | (otherbits << 16);
            u32* dst = (u32*)(sb0 + (size_t)bat*HDIM + (4*c + jj));
            __hip_atomic_store(dst, packed, __ATOMIC_RELAXED, __HIP_MEMORY_SCOPE_AGENT);
        }
        asm volatile("s_waitcnt vmcnt(0)" ::: "memory");  // release: stores acked at LLC
    }
    __syncthreads();
    if (tid == 0)
        __hip_atomic_store(&flags[c], 1u, __ATOMIC_RELAXED, __HIP_MEMORY_SCOPE_AGENT);

    const f16* sbufs[2] = { sb0, sb1 };
    const int arow = mt*16 + p;   // A-fragment batch row (row = lane%16)
    int t = 0, l = 0;
    unsigned guard = 0;

    for (int r = 0; r < NROUND; ++r) {
        // ---- wait: waves mt==0 poll the 128 producer blocks of their K-half ----
        const u32 tgt = (u32)(r + 1);
        if (mt == 0 && guard < (1u<<22)) {
            for (;;) {
                u32 f0 = __hip_atomic_load(&flags[kh*128 + ln],      __ATOMIC_RELAXED, __HIP_MEMORY_SCOPE_AGENT);
                u32 f1 = __hip_atomic_load(&flags[kh*128 + 64 + ln], __ATOMIC_RELAXED, __HIP_MEMORY_SCOPE_AGENT);
                if (__all(f0 >= tgt && f1 >= tgt)) break;
                if (++guard >= (1u<<22)) break;   // safety: never hang
                __builtin_amdgcn_s_sleep(2);
            }
        }
        __syncthreads();                      // all waves gated on both halves ready
        asm volatile("" ::: "memory");        // acquire: no cache op needed (reads are LLC-direct)

        const f16* sb = sbufs[r & 1];
        f32x4 acc = {0.f,0.f,0.f,0.f};
        {
            // A-fragment: agent-scope u64 loads straight from LLC (never stale)
            const u64* ap = (const u64*)(sb + (size_t)arow*HDIM + (size_t)kh*512);
            const f16* bp = lw + ((l*32 + kh*16)*12 + pe)*32 + g*8;
            #pragma unroll
            for (int kk = 0; kk < 16; ++kk) {
                u64 lo = __hip_atomic_load(ap + g*2 + kk*8,     __ATOMIC_RELAXED, __HIP_MEMORY_SCOPE_AGENT);
                u64 hi = __hip_atomic_load(ap + g*2 + kk*8 + 1, __ATOMIC_RELAXED, __HIP_MEMORY_SCOPE_AGENT);
                u64x2 q; q[0] = lo; q[1] = hi;
                f16x8 a = __builtin_bit_cast(f16x8, q);
                f16x8 b = *(const f16x8*)(bp + kk*384);
                acc = __builtin_amdgcn_mfma_f32_16x16x32_f16(a, b, acc, 0, 0, 0);
            }
        }
        if (l == 0) {  // fold input projections into layer 0 (slot 5); xT is read-only -> cached loads
            const f16* bp = lw + ((5*32 + kh*16)*12 + pe)*32 + g*8;
            if (USE_XT) {
                const f16* ap = xT + ((size_t)t*64 + arow)*HDIM + kh*512 + g*8;
                #pragma unroll
                for (int kk = 0; kk < 16; ++kk) {
                    f16x8 a = *(const f16x8*)(ap + kk*32);
                    f16x8 b = *(const f16x8*)(bp + kk*384);
                    acc = __builtin_amdgcn_mfma_f32_16x16x32_f16(a, b, acc, 0, 0, 0);
                }
            } else {
                const float* ap = x + ((size_t)arow*TSTEPS + t)*HDIM + kh*512 + g*8;
                #pragma unroll
                for (int kk = 0; kk < 16; ++kk) {
                    float4 v0 = *(const float4*)(ap + kk*32);
                    float4 v1 = *(const float4*)(ap + kk*32 + 4);
                    f16x8 a;
                    a[0]=(f16)v0.x; a[1]=(f16)v0.y; a[2]=(f16)v0.z; a[3]=(f16)v0.w;
                    a[4]=(f16)v1.x; a[5]=(f16)v1.y; a[6]=(f16)v1.z; a[7]=(f16)v1.w;
                    f16x8 b = *(const f16x8*)(bp + kk*384);
                    acc = __builtin_amdgcn_mfma_f32_16x16x32_f16(a, b, acc, 0, 0, 0);
                }
            }
        }
        if (kh == 1) red[mt*64 + ln] = acc;
        __syncthreads();
        if (kh == 0) {
            acc += red[mt*64 + ln];
            // redistribute: lane u=(R,jj) gathers H/T/C from lanes (R>>2)*16 + jj + {0,4,8}, reg R&3
            const int sl = (R >> 2)*16 + jj;
            const int ri = R & 3;
            float hv, tv, cv;
            { float v0=__shfl(acc[0],sl),   v1=__shfl(acc[1],sl),   v2=__shfl(acc[2],sl),   v3=__shfl(acc[3],sl);
              hv = ri==0?v0: ri==1?v1: ri==2?v2: v3; }
            { float v0=__shfl(acc[0],sl+4), v1=__shfl(acc[1],sl+4), v2=__shfl(acc[2],sl+4), v3=__shfl(acc[3],sl+4);
              tv = ri==0?v0: ri==1?v1: ri==2?v2: v3; }
            { float v0=__shfl(acc[0],sl+8), v1=__shfl(acc[1],sl+8), v2=__shfl(acc[2],sl+8), v3=__shfl(acc[3],sl+8);
              cv = ri==0?v0: ri==1?v1: ri==2?v2: v3; }
            hv += bh[l]; tv += bt[l]; cv += bc[l];
            const float hh = ftanh(hv);
            const float tg = fsigmoid(tv);
            const float cg = fsigmoid(cv);
            const float s_new = hh*tg + s_cur*cg;
            s_cur = s_new;
            f16* sbn = (f16*)sbufs[(r + 1) & 1];
            // packed u32 agent-scope store (LLC-direct)
            union { f16 h; unsigned short u; } cv2; cv2.h = (f16)s_new;
            u32 mybits = cv2.u;
            u32 otherbits = (u32)(unsigned short)__shfl_xor((int)mybits, 1);
            if ((jj & 1) == 0) {
                u32 packed = mybits | (otherbits << 16);
                u32* dst = (u32*)(sbn + (size_t)bat*HDIM + (4*c + jj));
                __hip_atomic_store(dst, packed, __ATOMIC_RELAXED, __HIP_MEMORY_SCOPE_AGENT);
            }
            if (l == NL-1) out[((size_t)bat*TSTEPS + t)*HDIM + jcol] = s_new;
            asm volatile("s_waitcnt vmcnt(0)" ::: "memory");  // release: s stores acked at LLC
        }
        __syncthreads();
        if (tid == 0)
            __hip_atomic_store(&flags[c], (u32)(r + 2), __ATOMIC_RELAXED, __HIP_MEMORY_SCOPE_AGENT);

        if (++l == NL) { l = 0; ++t; }
    }
    // s_final tail
    if (kh == 0)
        out[(size_t)64*TSTEPS*HDIM + (size_t)bat*HDIM + jcol] = s_cur;
}

extern "C" void kernel_launch(void* const* d_in, const int* in_sizes, int n_in,
                              void* d_out, int out_size, void* d_ws, size_t ws_size,
                              hipStream_t stream)
{
    const float* x    = (const float*)d_in[0];
    const float* s0   = (const float*)d_in[1];
    const float* w_h  = (const float*)d_in[2];
    const float* w_t  = (const float*)d_in[3];
    const float* w_c  = (const float*)d_in[4];
    const float* r_hw = (const float*)d_in[5];
    const float* r_tw = (const float*)d_in[6];
    const float* r_cw = (const float*)d_in[7];
    const float* r_hb = (const float*)d_in[8];
    const float* r_tb = (const float*)d_in[9];
    const float* r_cb = (const float*)d_in[10];
    float* out = (float*)d_out;

    char* ws   = (char*)d_ws;
    u32*  flags = (u32*)ws;                                 // 1 KB
    f16*  sb0  = (f16*)(ws + 4096);                         // 128 KB
    f16*  sb1  = (f16*)(ws + 4096 + 131072);                // 128 KB
    f16*  xT   = (f16*)(ws + 4096 + 262144);                // 64 MB
    const size_t need_xt = 4096 + 262144 + (size_t)TSTEPS*64*HDIM*2;
    const bool use_xt = (ws_size >= need_xt);

    hipMemsetAsync(flags, 0, 1024, stream);
    if (use_xt)
        cvt_x_kernel<<<dim3(16384), dim3(256), 0, stream>>>(x, xT);

    hipFuncSetAttribute((const void*)rhn_persistent<true>,
                        hipFuncAttributeMaxDynamicSharedMemorySize, SMEM_BYTES);
    hipFuncSetAttribute((const void*)rhn_persistent<false>,
                        hipFuncAttributeMaxDynamicSharedMemorySize, SMEM_BYTES);

    if (use_xt)
        rhn_persistent<true><<<dim3(NBLK), dim3(TPB), SMEM_BYTES, stream>>>(
            x, xT, s0, w_h, w_t, w_c, r_hw, r_tw, r_cw, r_hb, r_tb, r_cb,
            sb0, sb1, flags, out);
    else
        rhn_persistent<false><<<dim3(NBLK), dim3(TPB), SMEM_BYTES, stream>>>(
            x, xT, s0, w_h, w_t, w_c, r_hw, r_tw, r_cw, r_hb, r_tb, r_cb,
            sb0, sb1, flags, out);
}

// Round 3
// 17295.839 us; speedup vs baseline: 5.9343x; 1.8847x over previous
//
#include <hip/hip_runtime.h>

typedef _Float16 f16;
typedef f16  f16x8 __attribute__((ext_vector_type(8)));
typedef float f32x4 __attribute__((ext_vector_type(4)));
typedef unsigned int u32;
typedef unsigned long long u64;

#define NBLK   256
#define TPB    512
#define TSTEPS 512
#define NL     5
#define HDIM   1024
#define NROUND (TSTEPS*NL)
#define WSLOT  6
// LDS weights: [slot(6)][kk(32)][pe(12)][g'(4)*8+i(8)] halfs, g' swizzled
#define LDS_RED_OFF 147456
#define SMEM_BYTES  (147456 + 4096)        // 151552 B

__device__ __forceinline__ float fsigmoid(float v){ return 1.0f/(1.0f + __expf(-v)); }
__device__ __forceinline__ float ftanh(float v){ return 1.0f - 2.0f/(__expf(2.0f*v) + 1.0f); }

// Fragment-order state layout (128 KB per state image):
//   byte[ ((kh*4+mt)*16 + kk)*1024 + ln*16 + i*2 ] = s[mt*16 + (ln&15)][kh*512 + kk*32 + (ln>>4)*8 + i]
// Inverse for element (row,col):
//   mt=row>>4, pp=row&15, kh=col>>9, kk=(col>>5)&15, g8=(col>>3)&3, i=col&7
//   off_bytes = ((kh*4+mt)*16+kk)*1024 + (g8*16+pp)*16 + i*2
__device__ __forceinline__ size_t frag_off_bytes(int row, int col){
    const int mt = row >> 4, pp = row & 15;
    const int kh = col >> 9, kk = (col >> 5) & 15, g8 = (col >> 3) & 3, i = col & 7;
    return (size_t)(((kh*4 + mt)*16 + kk)*1024 + (g8*16 + pp)*16 + i*2);
}

// x [B][T][K] f32 -> xT [T] x fragment-order f16 blocks (128 KB each)
__global__ void cvt_x_kernel(const float* __restrict__ x, f16* __restrict__ xT){
    const size_t idx = (size_t)blockIdx.x*blockDim.x + threadIdx.x;
    const size_t e = idx*8;
    const int k  = (int)(e & 1023);
    const int tt = (int)((e >> 10) & 511);
    const int b  = (int)(e >> 19);
    const float4 v0 = *(const float4*)(x + e);
    const float4 v1 = *(const float4*)(x + e + 4);
    f16x8 o;
    o[0]=(f16)v0.x; o[1]=(f16)v0.y; o[2]=(f16)v0.z; o[3]=(f16)v0.w;
    o[4]=(f16)v1.x; o[5]=(f16)v1.y; o[6]=(f16)v1.z; o[7]=(f16)v1.w;
    char* dst = (char*)xT + (size_t)tt*131072 + frag_off_bytes(b, k);  // k%8==0 -> 16B aligned
    *(f16x8*)dst = o;
}

#define LOADA(i) asm volatile("global_load_dwordx4 %0, %1, off sc0 sc1" : "=v"(a##i) : "v"(ap + (i)*1024))

template<bool USE_XT>
__global__ __launch_bounds__(TPB, 2)
void rhn_persistent(const float* __restrict__ x,   // f32 [64][512][1024], used if !USE_XT
                    const f16*  __restrict__ xT,   // fragment-order f16, used if USE_XT
                    const float* __restrict__ s0,
                    const float* __restrict__ w_h, const float* __restrict__ w_t, const float* __restrict__ w_c,
                    const float* __restrict__ r_hw, const float* __restrict__ r_tw, const float* __restrict__ r_cw,
                    const float* __restrict__ r_hb, const float* __restrict__ r_tb, const float* __restrict__ r_cb,
                    f16* __restrict__ sb0, f16* __restrict__ sb1,
                    u32* __restrict__ flags,
                    float* __restrict__ out)
{
    extern __shared__ char smem[];
    f16*   lw  = (f16*)smem;
    f32x4* red = (f32x4*)(smem + LDS_RED_OFF);   // [4 waves][64 lanes]

    const int tid = threadIdx.x;
    const int ln  = tid & 63;
    const int wid = tid >> 6;
    const int mt  = wid & 3;   // M-tile (batches mt*16..+16)
    const int kh  = wid >> 2;  // K-half (0: k<512, 1: k>=512)
    const int c   = blockIdx.x;
    const int g   = ln >> 4;   // k-group within 32-k tile
    const int p   = ln & 15;   // packed col: 0-3 h, 4-7 t, 8-11 c, 12-15 pad
    const int pe  = (p < 12) ? p : 11;
    const int gsw = (g + (pe >> 1)) & 3;          // bank-conflict swizzle

    // ---------------- prologue: LDS weight fill (swizzled g') ----------------
    for (int s = 0; s < WSLOT; ++s) {
        for (int mu = 0; mu < 3; ++mu) {
            const float* W;
            if (s < NL) W = (mu==0 ? r_hw : (mu==1 ? r_tw : r_cw)) + (size_t)s*HDIM*HDIM;
            else        W = (mu==0 ? w_h  : (mu==1 ? w_t  : w_c));
            for (int k = tid; k < HDIM; k += TPB) {
                const float4 v = *(const float4*)(W + (size_t)k*HDIM + 4*c);  // cols 4c..4c+3
                const int kk = k >> 5, gg = (k >> 3) & 3, ii = k & 7;
                #pragma unroll
                for (int w = 0; w < 4; ++w) {
                    const int pe2 = mu*4 + w;
                    const int gs  = (gg + (pe2 >> 1)) & 3;
                    const float val = (w==0) ? v.x : (w==1) ? v.y : (w==2) ? v.z : v.w;
                    lw[((s*32 + kk)*12 + pe2)*32 + gs*8 + ii] = (f16)val;
                }
            }
        }
    }

    // per-lane ownership for update waves (kh==0): lane -> (batch row R, col jj)
    const int R    = ln >> 2;
    const int jj   = ln & 3;
    const int jcol = 4*c + jj;
    const int bat  = mt*16 + R;
    const size_t sfoff = frag_off_bytes(bat, jcol & ~1);  // u32-aligned slot for lane pair
    float s_cur = 0.f;
    float bh[NL], bt[NL], bc[NL];
    if (kh == 0) {
        s_cur = s0[(size_t)bat*HDIM + jcol];
        #pragma unroll
        for (int l = 0; l < NL; ++l) {
            bh[l] = r_hb[l*HDIM + jcol];
            bt[l] = r_tb[l*HDIM + jcol];
            bc[l] = r_cb[l*HDIM + jcol];
        }
        union { f16 h; unsigned short u; } cv; cv.h = (f16)s_cur;
        u32 mybits = cv.u;
        u32 otherbits = (u32)(unsigned short)__shfl_xor((int)mybits, 1);
        if ((jj & 1) == 0) {
            u32 packed = mybits | (otherbits << 16);
            u32* dst = (u32*)((char*)sb0 + sfoff);
            __hip_atomic_store(dst, packed, __ATOMIC_RELAXED, __HIP_MEMORY_SCOPE_AGENT);
        }
        asm volatile("s_waitcnt vmcnt(0)" ::: "memory");  // release: stores acked at LLC
    }
    __syncthreads();
    if (tid == 0)
        __hip_atomic_store(&flags[c], 1u, __ATOMIC_RELAXED, __HIP_MEMORY_SCOPE_AGENT);

    const f16* sbufs[2] = { sb0, sb1 };
    int t = 0, l = 0;
    unsigned guard = 0;

    for (int r = 0; r < NROUND; ++r) {
        // ---- wait: waves mt==0 poll the 128 producer blocks of their K-half ----
        const u32 tgt = (u32)(r + 1);
        if (mt == 0 && guard < (1u<<22)) {
            const u64* fp = (const u64*)&flags[kh*128 + 2*ln];
            for (;;) {
                u64 ff = __hip_atomic_load(fp, __ATOMIC_RELAXED, __HIP_MEMORY_SCOPE_AGENT);
                if (__all((u32)ff >= tgt && (u32)(ff >> 32) >= tgt)) break;
                if (++guard >= (1u<<22)) break;   // safety: never hang
                __builtin_amdgcn_s_sleep(2);
            }
        }
        __syncthreads();                      // all waves gated on both halves ready

        const char* ap = (const char*)sbufs[r & 1] + (size_t)((kh*4 + mt)*16)*1024 + ln*16;
        f16x8 a0,a1,a2,a3,a4,a5,a6,a7,a8,a9,a10,a11,a12,a13,a14,a15;
        LOADA(0);  LOADA(1);  LOADA(2);  LOADA(3);
        LOADA(4);  LOADA(5);  LOADA(6);  LOADA(7);
        LOADA(8);  LOADA(9);  LOADA(10); LOADA(11);
        LOADA(12); LOADA(13); LOADA(14); LOADA(15);

        f32x4 acc = {0.f,0.f,0.f,0.f};
        const f16* bp = lw + ((l*32 + kh*16)*12 + pe)*32 + gsw*8;

        if (l == 0) {  // fold input projections into layer 0 (slot 5) under A-load shadow
            const f16* bp5 = lw + ((5*32 + kh*16)*12 + pe)*32 + gsw*8;
            if (USE_XT) {
                const f16* xp = xT + (size_t)t*65536 + (size_t)((kh*4 + mt)*16)*512 + ln*8;
                #pragma unroll
                for (int kk = 0; kk < 16; ++kk) {
                    f16x8 xa = *(const f16x8*)(xp + kk*512);
                    f16x8 b  = *(const f16x8*)(bp5 + kk*384);
                    acc = __builtin_amdgcn_mfma_f32_16x16x32_f16(xa, b, acc, 0, 0, 0);
                }
            } else {
                const int arow = mt*16 + p;
                const float* xp = x + ((size_t)arow*TSTEPS + t)*HDIM + kh*512 + g*8;
                #pragma unroll
                for (int kk = 0; kk < 16; ++kk) {
                    float4 v0 = *(const float4*)(xp + kk*32);
                    float4 v1 = *(const float4*)(xp + kk*32 + 4);
                    f16x8 xa;
                    xa[0]=(f16)v0.x; xa[1]=(f16)v0.y; xa[2]=(f16)v0.z; xa[3]=(f16)v0.w;
                    xa[4]=(f16)v1.x; xa[5]=(f16)v1.y; xa[6]=(f16)v1.z; xa[7]=(f16)v1.w;
                    f16x8 b = *(const f16x8*)(bp5 + kk*384);
                    acc = __builtin_amdgcn_mfma_f32_16x16x32_f16(xa, b, acc, 0, 0, 0);
                }
            }
        }

        asm volatile("s_waitcnt vmcnt(0)" ::: "memory");   // A loads landed
        __builtin_amdgcn_sched_barrier(0);                 // rule #18: nothing crosses
        acc = __builtin_amdgcn_mfma_f32_16x16x32_f16(a0,  *(const f16x8*)(bp + 0*384),  acc, 0,0,0);
        acc = __builtin_amdgcn_mfma_f32_16x16x32_f16(a1,  *(const f16x8*)(bp + 1*384),  acc, 0,0,0);
        acc = __builtin_amdgcn_mfma_f32_16x16x32_f16(a2,  *(const f16x8*)(bp + 2*384),  acc, 0,0,0);
        acc = __builtin_amdgcn_mfma_f32_16x16x32_f16(a3,  *(const f16x8*)(bp + 3*384),  acc, 0,0,0);
        acc = __builtin_amdgcn_mfma_f32_16x16x32_f16(a4,  *(const f16x8*)(bp + 4*384),  acc, 0,0,0);
        acc = __builtin_amdgcn_mfma_f32_16x16x32_f16(a5,  *(const f16x8*)(bp + 5*384),  acc, 0,0,0);
        acc = __builtin_amdgcn_mfma_f32_16x16x32_f16(a6,  *(const f16x8*)(bp + 6*384),  acc, 0,0,0);
        acc = __builtin_amdgcn_mfma_f32_16x16x32_f16(a7,  *(const f16x8*)(bp + 7*384),  acc, 0,0,0);
        acc = __builtin_amdgcn_mfma_f32_16x16x32_f16(a8,  *(const f16x8*)(bp + 8*384),  acc, 0,0,0);
        acc = __builtin_amdgcn_mfma_f32_16x16x32_f16(a9,  *(const f16x8*)(bp + 9*384),  acc, 0,0,0);
        acc = __builtin_amdgcn_mfma_f32_16x16x32_f16(a10, *(const f16x8*)(bp + 10*384), acc, 0,0,0);
        acc = __builtin_amdgcn_mfma_f32_16x16x32_f16(a11, *(const f16x8*)(bp + 11*384), acc, 0,0,0);
        acc = __builtin_amdgcn_mfma_f32_16x16x32_f16(a12, *(const f16x8*)(bp + 12*384), acc, 0,0,0);
        acc = __builtin_amdgcn_mfma_f32_16x16x32_f16(a13, *(const f16x8*)(bp + 13*384), acc, 0,0,0);
        acc = __builtin_amdgcn_mfma_f32_16x16x32_f16(a14, *(const f16x8*)(bp + 14*384), acc, 0,0,0);
        acc = __builtin_amdgcn_mfma_f32_16x16x32_f16(a15, *(const f16x8*)(bp + 15*384), acc, 0,0,0);

        if (kh == 1) red[mt*64 + ln] = acc;
        __syncthreads();
        if (kh == 0) {
            acc += red[mt*64 + ln];
            // redistribute: lane u=(R,jj) gathers H/T/C from lanes (R>>2)*16 + jj + {0,4,8}, reg R&3
            const int sl = (R >> 2)*16 + jj;
            const int ri = R & 3;
            float hv, tv, cv;
            { float v0=__shfl(acc[0],sl),   v1=__shfl(acc[1],sl),   v2=__shfl(acc[2],sl),   v3=__shfl(acc[3],sl);
              hv = ri==0?v0: ri==1?v1: ri==2?v2: v3; }
            { float v0=__shfl(acc[0],sl+4), v1=__shfl(acc[1],sl+4), v2=__shfl(acc[2],sl+4), v3=__shfl(acc[3],sl+4);
              tv = ri==0?v0: ri==1?v1: ri==2?v2: v3; }
            { float v0=__shfl(acc[0],sl+8), v1=__shfl(acc[1],sl+8), v2=__shfl(acc[2],sl+8), v3=__shfl(acc[3],sl+8);
              cv = ri==0?v0: ri==1?v1: ri==2?v2: v3; }
            hv += bh[l]; tv += bt[l]; cv += bc[l];
            const float hh = ftanh(hv);
            const float tg = fsigmoid(tv);
            const float cg = fsigmoid(cv);
            const float s_new = hh*tg + s_cur*cg;
            s_cur = s_new;
            f16* sbn = (f16*)sbufs[(r + 1) & 1];
            union { f16 h; unsigned short u; } cv2; cv2.h = (f16)s_new;
            u32 mybits = cv2.u;
            u32 otherbits = (u32)(unsigned short)__shfl_xor((int)mybits, 1);
            if ((jj & 1) == 0) {
                u32 packed = mybits | (otherbits << 16);
                u32* dst = (u32*)((char*)sbn + sfoff);
                __hip_atomic_store(dst, packed, __ATOMIC_RELAXED, __HIP_MEMORY_SCOPE_AGENT);
            }
            if (l == NL-1) out[((size_t)bat*TSTEPS + t)*HDIM + jcol] = s_new;
            asm volatile("s_waitcnt vmcnt(0)" ::: "memory");  // release: s stores acked at LLC
        }
        __syncthreads();
        if (tid == 0)
            __hip_atomic_store(&flags[c], (u32)(r + 2), __ATOMIC_RELAXED, __HIP_MEMORY_SCOPE_AGENT);

        if (++l == NL) { l = 0; ++t; }
    }
    // s_final tail
    if (kh == 0)
        out[(size_t)64*TSTEPS*HDIM + (size_t)bat*HDIM + jcol] = s_cur;
}

extern "C" void kernel_launch(void* const* d_in, const int* in_sizes, int n_in,
                              void* d_out, int out_size, void* d_ws, size_t ws_size,
                              hipStream_t stream)
{
    const float* x    = (const float*)d_in[0];
    const float* s0   = (const float*)d_in[1];
    const float* w_h  = (const float*)d_in[2];
    const float* w_t  = (const float*)d_in[3];
    const float* w_c  = (const float*)d_in[4];
    const float* r_hw = (const float*)d_in[5];
    const float* r_tw = (const float*)d_in[6];
    const float* r_cw = (const float*)d_in[7];
    const float* r_hb = (const float*)d_in[8];
    const float* r_tb = (const float*)d_in[9];
    const float* r_cb = (const float*)d_in[10];
    float* out = (float*)d_out;

    char* ws   = (char*)d_ws;
    u32*  flags = (u32*)ws;                                 // 1 KB
    f16*  sb0  = (f16*)(ws + 4096);                         // 128 KB
    f16*  sb1  = (f16*)(ws + 4096 + 131072);                // 128 KB
    f16*  xT   = (f16*)(ws + 4096 + 262144);                // 64 MB
    const size_t need_xt = 4096 + 262144 + (size_t)TSTEPS*64*HDIM*2;
    const bool use_xt = (ws_size >= need_xt);

    hipMemsetAsync(flags, 0, 1024, stream);
    if (use_xt)
        cvt_x_kernel<<<dim3(16384), dim3(256), 0, stream>>>(x, xT);

    hipFuncSetAttribute((const void*)rhn_persistent<true>,
                        hipFuncAttributeMaxDynamicSharedMemorySize, SMEM_BYTES);
    hipFuncSetAttribute((const void*)rhn_persistent<false>,
                        hipFuncAttributeMaxDynamicSharedMemorySize, SMEM_BYTES);

    if (use_xt)
        rhn_persistent<true><<<dim3(NBLK), dim3(TPB), SMEM_BYTES, stream>>>(
            x, xT, s0, w_h, w_t, w_c, r_hw, r_tw, r_cw, r_hb, r_tb, r_cb,
            sb0, sb1, flags, out);
    else
        rhn_persistent<false><<<dim3(NBLK), dim3(TPB), SMEM_BYTES, stream>>>(
            x, xT, s0, w_h, w_t, w_c, r_hw, r_tw, r_cw, r_hb, r_tb, r_cb,
            sb0, sb1, flags, out);
}